// Round 1
// baseline (2589.240 us; speedup 1.0000x reference)
//
#include <hip/hip_runtime.h>
#include <hip/hip_bf16.h>

// Problem constants
constexpr int BB  = 64;     // batch
constexpr int PP  = 196;    // pixels
constexpr int CENC = 2048;  // encoder dim
constexpr int HH  = 512;    // hidden
constexpr int AA  = 512;    // attention dim
constexpr int EE  = 512;    // embed dim
constexpr int VV  = 10000;  // vocab
constexpr int TT  = 20;     // caption length
constexpr int TM1 = 19;     // decode steps

// ---------------------------------------------------------------------------
// Generic f32 GEMM: C[M,N] = A[M,K] @ W[N,K]^T (+bias, per OP/MODE)
// MODE 0: single W1 (+b1)
// MODE 1: n-split at `split`: n<split -> W1/b1 row n ; else W2/b2 row n-split
// MODE 2: k-split at `split`: k<split -> W1[n][k] ; else W2[n][k-split]; bias=b1[n]+b2[n]
// OP 0: full store + bias
// OP 1: pred epilogue: row r = t*64+b -> out[(b*TM1+t)*VV + n], masked by t < len[b]-1
// OP 2: k-chunk partial store (no bias): C[(blockIdx.z*M + m)*ldc + n]
// Tiles: BM=64, BN=64, BK=32, 256 threads, 4x4 accum/thread.
// ---------------------------------------------------------------------------
template<int MODE, int OP>
__global__ __launch_bounds__(256)
void gemm64(const float* __restrict__ Amat, int lda,
            const float* __restrict__ W1, int ldw1, const float* __restrict__ b1,
            const float* __restrict__ W2, int ldw2, const float* __restrict__ b2,
            int split, int kcK,
            float* __restrict__ C, int ldc, int M, int N, int K,
            const int* __restrict__ lengths)
{
    __shared__ __align__(16) float As[32][64];
    __shared__ __align__(16) float Ws[32][64];

    const int tid = threadIdx.x;
    const int n0 = blockIdx.x * 64;
    const int m0 = blockIdx.y * 64;
    const int kz = blockIdx.z;
    const int k0 = kz * kcK;
    const int kend = min(K, k0 + kcK);

    const int ty = tid >> 4, tx = tid & 15;
    float acc[4][4] = {};

    for (int kt = k0; kt < kend; kt += 32) {
        // ---- load A tile (64 rows x 32 cols) as 512 float4 slots ----
        #pragma unroll
        for (int i = 0; i < 2; ++i) {
            int idx = tid + i * 256;
            int row = idx >> 3, c4 = (idx & 7) * 4;
            int m = m0 + row;
            float4 v = make_float4(0.f, 0.f, 0.f, 0.f);
            if (m < M)
                v = *reinterpret_cast<const float4*>(&Amat[(size_t)m * lda + kt + c4]);
            As[c4 + 0][row] = v.x; As[c4 + 1][row] = v.y;
            As[c4 + 2][row] = v.z; As[c4 + 3][row] = v.w;
        }
        // ---- load W tile ----
        #pragma unroll
        for (int i = 0; i < 2; ++i) {
            int idx = tid + i * 256;
            int row = idx >> 3, c4 = (idx & 7) * 4;
            int n = n0 + row;
            int kk = kt + c4;
            float4 v = make_float4(0.f, 0.f, 0.f, 0.f);
            if (n < N) {
                const float* wr;
                if (MODE == 1) {
                    wr = (n < split) ? &W1[(size_t)n * ldw1 + kk]
                                     : &W2[(size_t)(n - split) * ldw2 + kk];
                } else if (MODE == 2) {
                    wr = (kk < split) ? &W1[(size_t)n * ldw1 + kk]
                                      : &W2[(size_t)n * ldw2 + (kk - split)];
                } else {
                    wr = &W1[(size_t)n * ldw1 + kk];
                }
                v = *reinterpret_cast<const float4*>(wr);
            }
            Ws[c4 + 0][row] = v.x; Ws[c4 + 1][row] = v.y;
            Ws[c4 + 2][row] = v.z; Ws[c4 + 3][row] = v.w;
        }
        __syncthreads();
        // ---- inner product ----
        #pragma unroll
        for (int kk = 0; kk < 32; ++kk) {
            float av[4], bv[4];
            *reinterpret_cast<float4*>(av) = *reinterpret_cast<const float4*>(&As[kk][ty * 4]);
            *reinterpret_cast<float4*>(bv) = *reinterpret_cast<const float4*>(&Ws[kk][tx * 4]);
            #pragma unroll
            for (int ii = 0; ii < 4; ++ii)
                #pragma unroll
                for (int jj = 0; jj < 4; ++jj)
                    acc[ii][jj] = fmaf(av[ii], bv[jj], acc[ii][jj]);
        }
        __syncthreads();
    }

    // ---- epilogue ----
    if (OP == 2) {
        #pragma unroll
        for (int ii = 0; ii < 4; ++ii) {
            int m = m0 + ty * 4 + ii;
            if (m >= M) continue;
            #pragma unroll
            for (int jj = 0; jj < 4; ++jj) {
                int n = n0 + tx * 4 + jj;
                if (n < N) C[((size_t)kz * M + m) * ldc + n] = acc[ii][jj];
            }
        }
    } else if (OP == 0) {
        #pragma unroll
        for (int ii = 0; ii < 4; ++ii) {
            int m = m0 + ty * 4 + ii;
            if (m >= M) continue;
            #pragma unroll
            for (int jj = 0; jj < 4; ++jj) {
                int n = n0 + tx * 4 + jj;
                if (n >= N) continue;
                float bias;
                if (MODE == 1)      bias = (n < split) ? b1[n] : b2[n - split];
                else if (MODE == 2) bias = b1[n] + b2[n];
                else                bias = b1[n];
                C[(size_t)m * ldc + n] = acc[ii][jj] + bias;
            }
        }
    } else { // OP == 1 : prediction epilogue with active mask + row remap
        #pragma unroll
        for (int ii = 0; ii < 4; ++ii) {
            int r = m0 + ty * 4 + ii;
            if (r >= M) continue;
            int t = r >> 6, b = r & 63;
            bool active = t < (lengths[b] - 1);
            #pragma unroll
            for (int jj = 0; jj < 4; ++jj) {
                int n = n0 + tx * 4 + jj;
                if (n >= N) continue;
                C[((size_t)b * TM1 + t) * VV + n] = active ? (acc[ii][jj] + b1[n]) : 0.f;
            }
        }
    }
}

// mean over P: grid (64, 8), 256 thr; block (b,kc) handles k = kc*256 + tid
__global__ __launch_bounds__(256)
void kMean(const float* __restrict__ enc, float* __restrict__ mean)
{
    int b = blockIdx.x;
    int k = blockIdx.y * 256 + threadIdx.x;
    const float* eb = &enc[(size_t)b * PP * CENC + k];
    float s0 = 0, s1 = 0, s2 = 0, s3 = 0;
    int p = 0;
    for (; p + 4 <= PP; p += 4) {
        s0 += eb[(size_t)(p + 0) * CENC];
        s1 += eb[(size_t)(p + 1) * CENC];
        s2 += eb[(size_t)(p + 2) * CENC];
        s3 += eb[(size_t)(p + 3) * CENC];
    }
    for (; p < PP; ++p) s0 += eb[(size_t)p * CENC];
    mean[b * CENC + k] = ((s0 + s1) + (s2 + s3)) * (1.0f / PP);
}

// reduce h0/c0 partials (4 chunks) + bias -> hc[64][1024] (h = [:,0:512], c = [:,512:1024])
__global__ __launch_bounds__(256)
void kReduceHC(const float* __restrict__ Pc, const float* __restrict__ hb,
               const float* __restrict__ cb, float* __restrict__ hc)
{
    int b = blockIdx.x, tid = threadIdx.x;
    for (int j = tid; j < 1024; j += 256) {
        float s = Pc[((size_t)0 * BB + b) * 1024 + j] + Pc[((size_t)1 * BB + b) * 1024 + j]
                + Pc[((size_t)2 * BB + b) * 1024 + j] + Pc[((size_t)3 * BB + b) * 1024 + j];
        s += (j < 512) ? hb[j] : cb[j - 512];
        hc[b * 1024 + j] = s;
    }
}

// Attention part 1 (per-b block): att2 reduce, e, softmax, alpha; emb gather + h copy into xh.
__global__ __launch_bounds__(256)
void kATT1(const float* __restrict__ att1, const float* __restrict__ P3,
           const float* __restrict__ hid_b, const float* __restrict__ faw,
           const float* __restrict__ fab,
           const int* __restrict__ captions, const int* __restrict__ lengths,
           const float* __restrict__ embw, const float* __restrict__ hc,
           float* __restrict__ alpha, float* __restrict__ alpha_out,
           float* __restrict__ xh, int t)
{
    int b = blockIdx.x, tid = threadIdx.x;
    __shared__ float att2s[AA];
    __shared__ float fw[AA];
    __shared__ float es[PP];
    __shared__ float red[8];

    for (int a = tid; a < AA; a += 256) {
        float s = hid_b[a];
        #pragma unroll
        for (int sc = 0; sc < 4; ++sc) s += P3[((size_t)sc * BB + b) * 2560 + a];
        att2s[a] = s;
        fw[a] = faw[a];
    }
    __syncthreads();

    int wv = tid >> 6, lane = tid & 63;
    for (int p = wv; p < PP; p += 4) {
        const float* row = &att1[((size_t)b * PP + p) * AA];
        float s = 0.f;
        for (int a = lane; a < AA; a += 64) {
            float v = row[a] + att2s[a];
            s += fmaxf(v, 0.f) * fw[a];
        }
        #pragma unroll
        for (int off = 32; off > 0; off >>= 1) s += __shfl_down(s, off, 64);
        if (lane == 0) es[p] = s + fab[0];
    }
    __syncthreads();

    // softmax over 196
    float m = -1e30f;
    for (int p = tid; p < PP; p += 256) m = fmaxf(m, es[p]);
    #pragma unroll
    for (int off = 32; off > 0; off >>= 1) m = fmaxf(m, __shfl_down(m, off, 64));
    if (lane == 0) red[wv] = m;
    __syncthreads();
    m = fmaxf(fmaxf(red[0], red[1]), fmaxf(red[2], red[3]));
    float ssum = 0.f;
    for (int p = tid; p < PP; p += 256) { float ev = expf(es[p] - m); es[p] = ev; ssum += ev; }
    #pragma unroll
    for (int off = 32; off > 0; off >>= 1) ssum += __shfl_down(ssum, off, 64);
    if (lane == 0) red[4 + wv] = ssum;
    __syncthreads();
    float inv = 1.f / (red[4] + red[5] + red[6] + red[7]);
    bool active = t < (lengths[b] - 1);
    for (int p = tid; p < PP; p += 256) {
        float al = es[p] * inv;
        alpha[b * PP + p] = al;
        alpha_out[((size_t)b * TM1 + t) * PP + p] = active ? al : 0.f;
    }
    // embedding gather + h copy into xh
    int cap = captions[b * TT + t];
    for (int j = tid; j < 512; j += 256) {
        xh[(size_t)b * 3072 + j]        = embw[(size_t)cap * EE + j];
        xh[(size_t)b * 3072 + 2560 + j] = hc[b * 1024 + j];
    }
}

// Attention part 2: awe (alpha-weighted encoder sum) * sigmoid(gate) -> xh[:,512:2560]
// grid (64, 8): block (b, kc), k = kc*256 + tid
__global__ __launch_bounds__(256)
void kATT2(const float* __restrict__ enc, const float* __restrict__ alpha,
           const float* __restrict__ P3, const float* __restrict__ fbeta_b,
           float* __restrict__ xh)
{
    int b = blockIdx.x;
    int k = blockIdx.y * 256 + threadIdx.x;
    __shared__ float al[PP];
    for (int p = threadIdx.x; p < PP; p += 256) al[p] = alpha[b * PP + p];
    __syncthreads();

    const float* eb = &enc[(size_t)b * PP * CENC + k];
    float s0 = 0, s1 = 0, s2 = 0, s3 = 0;
    int p = 0;
    for (; p + 4 <= PP; p += 4) {
        s0 += al[p + 0] * eb[(size_t)(p + 0) * CENC];
        s1 += al[p + 1] * eb[(size_t)(p + 1) * CENC];
        s2 += al[p + 2] * eb[(size_t)(p + 2) * CENC];
        s3 += al[p + 3] * eb[(size_t)(p + 3) * CENC];
    }
    for (; p < PP; ++p) s0 += al[p] * eb[(size_t)p * CENC];
    float awe = (s0 + s1) + (s2 + s3);

    float graw = fbeta_b[k];
    #pragma unroll
    for (int sc = 0; sc < 4; ++sc) graw += P3[((size_t)sc * BB + b) * 2560 + 512 + k];
    float gate = 1.f / (1.f + expf(-graw));
    xh[(size_t)b * 3072 + 512 + k] = gate * awe;
}

// LSTM cell: reduce gates partials (8 chunks) + biases, update h,c, store h_new to allH
__global__ __launch_bounds__(256)
void kHC(const float* __restrict__ P4, const float* __restrict__ b_ih,
         const float* __restrict__ b_hh,
         float* __restrict__ hc, float* __restrict__ allH, int t)
{
    int b = blockIdx.x, tid = threadIdx.x;
    for (int j = tid; j < 512; j += 256) {
        float g4[4];
        #pragma unroll
        for (int q = 0; q < 4; ++q) {
            int col = q * 512 + j;
            float s = b_ih[col] + b_hh[col];
            #pragma unroll
            for (int sc = 0; sc < 8; ++sc) s += P4[((size_t)sc * BB + b) * 2048 + col];
            g4[q] = s;
        }
        float i_ = 1.f / (1.f + expf(-g4[0]));
        float f_ = 1.f / (1.f + expf(-g4[1]));
        float g_ = tanhf(g4[2]);
        float o_ = 1.f / (1.f + expf(-g4[3]));
        float c_new = f_ * hc[b * 1024 + 512 + j] + i_ * g_;
        float h_new = o_ * tanhf(c_new);
        hc[b * 1024 + 512 + j] = c_new;
        hc[b * 1024 + j] = h_new;
        allH[((size_t)t * BB + b) * HH + j] = h_new;
    }
}

extern "C" void kernel_launch(void* const* d_in, const int* in_sizes, int n_in,
                              void* d_out, int out_size, void* d_ws, size_t ws_size,
                              hipStream_t stream)
{
    const float* enc        = (const float*)d_in[0];
    const int*   captions   = (const int*)d_in[1];
    const int*   lengths    = (const int*)d_in[2];
    const float* enc_att_w  = (const float*)d_in[3];
    const float* enc_att_b  = (const float*)d_in[4];
    const float* hid_att_w  = (const float*)d_in[5];
    const float* hid_att_b  = (const float*)d_in[6];
    const float* full_att_w = (const float*)d_in[7];
    const float* full_att_b = (const float*)d_in[8];
    const float* embw       = (const float*)d_in[9];
    const float* w_ih       = (const float*)d_in[10];
    const float* w_hh       = (const float*)d_in[11];
    const float* b_ih       = (const float*)d_in[12];
    const float* b_hh       = (const float*)d_in[13];
    const float* init_h_w   = (const float*)d_in[14];
    const float* init_h_b   = (const float*)d_in[15];
    const float* init_c_w   = (const float*)d_in[16];
    const float* init_c_b   = (const float*)d_in[17];
    const float* fbeta_w    = (const float*)d_in[18];
    const float* fbeta_b    = (const float*)d_in[19];
    const float* fc_w       = (const float*)d_in[20];
    const float* fc_b       = (const float*)d_in[21];

    float* out_pred  = (float*)d_out;                           // [64][19][10000]
    float* out_alpha = out_pred + (size_t)BB * TM1 * VV;        // [64][19][196]
    float* att1      = out_pred;  // stash att1 [12544][512] in pred region (overwritten at the end)

    float* ws    = (float*)d_ws;
    float* mean  = ws;  ws += (size_t)BB * CENC;        // 131072
    float* hcP   = ws;  ws += (size_t)4 * BB * 1024;    // 262144
    float* hc    = ws;  ws += (size_t)BB * 1024;        // 65536
    float* P3    = ws;  ws += (size_t)4 * BB * 2560;    // 655360
    float* P4    = ws;  ws += (size_t)8 * BB * 2048;    // 1048576
    float* xh    = ws;  ws += (size_t)BB * 3072;        // 196608
    float* alpha = ws;  ws += (size_t)BB * PP;          // 12544
    float* allH  = ws;  ws += (size_t)TM1 * BB * HH;    // 622592  (total ~12 MB)

    // ---- precompute ----
    hipLaunchKernelGGL(kMean, dim3(64, 8), dim3(256), 0, stream, enc, mean);

    // h0|c0 = mean @ [init_h_w ; init_c_w]^T  (k-split x4 partials)
    hipLaunchKernelGGL((gemm64<1, 2>), dim3(16, 1, 4), dim3(256), 0, stream,
        mean, CENC, init_h_w, CENC, nullptr, init_c_w, CENC, nullptr, 512, 512,
        hcP, 1024, 64, 1024, CENC, nullptr);
    hipLaunchKernelGGL(kReduceHC, dim3(64), dim3(256), 0, stream, hcP, init_h_b, init_c_b, hc);

    // att1 = enc @ enc_att_w^T + b  -> [12544][512] (stored in d_out pred region)
    hipLaunchKernelGGL((gemm64<0, 0>), dim3(8, 196, 1), dim3(256), 0, stream,
        enc, CENC, enc_att_w, CENC, enc_att_b, nullptr, 0, nullptr, 0, CENC,
        att1, 512, BB * PP, 512, CENC, nullptr);

    // ---- sequential decode ----
    for (int t = 0; t < TM1; ++t) {
        // [att2 | gate_raw] = h @ [hid_att_w ; fbeta_w]^T  (k-split x4 partials)
        hipLaunchKernelGGL((gemm64<1, 2>), dim3(40, 1, 4), dim3(256), 0, stream,
            hc, 1024, hid_att_w, 512, nullptr, fbeta_w, 512, nullptr, 512, 128,
            P3, 2560, 64, 2560, 512, nullptr);

        hipLaunchKernelGGL(kATT1, dim3(64), dim3(256), 0, stream,
            att1, P3, hid_att_b, full_att_w, full_att_b, captions, lengths,
            embw, hc, alpha, out_alpha, xh, t);

        hipLaunchKernelGGL(kATT2, dim3(64, 8), dim3(256), 0, stream,
            enc, alpha, P3, fbeta_b, xh);

        // gates = xh @ [W_ih | W_hh]^T  (k-split x8 partials)
        hipLaunchKernelGGL((gemm64<2, 2>), dim3(32, 1, 8), dim3(256), 0, stream,
            xh, 3072, w_ih, 2560, nullptr, w_hh, 512, nullptr, 2560, 384,
            P4, 2048, 64, 2048, 3072, nullptr);

        hipLaunchKernelGGL(kHC, dim3(64), dim3(256), 0, stream, P4, b_ih, b_hh, hc, allH, t);
    }

    // ---- deferred prediction GEMM: [1216 x 10000], K=512, masked epilogue ----
    hipLaunchKernelGGL((gemm64<0, 1>), dim3(157, 19, 1), dim3(256), 0, stream,
        allH, 512, fc_w, 512, fc_b, nullptr, 0, nullptr, 0, 512,
        out_pred, 10000, TM1 * BB, VV, 512, lengths);
}

// Round 2
// 1557.507 us; speedup vs baseline: 1.6624x; 1.6624x over previous
//
#include <hip/hip_runtime.h>
#include <hip/hip_bf16.h>

typedef short short8 __attribute__((ext_vector_type(8)));
typedef float floatx4 __attribute__((ext_vector_type(4)));
typedef int   int4v  __attribute__((ext_vector_type(4)));

constexpr int BB = 64, PP = 196, CENC = 2048, HH = 512, AA = 512, EE = 512;
constexpr int VV = 10000, TT = 20, TM1 = 19;
constexpr int NCAT = 4608;  // 512 (att) + 2048 (fbeta) + 2048 (Whh)

__device__ __forceinline__ float bf2f(short u) {
    union { unsigned u; float f; } v; v.u = ((unsigned)(unsigned short)u) << 16; return v.f;
}
__device__ __forceinline__ short f2bf(float f) {
    union { float f; unsigned u; } v; v.f = f;
    unsigned r = v.u + 0x7FFF + ((v.u >> 16) & 1);
    return (short)(r >> 16);
}

// ---------------------------------------------------------------------------
// Weight prep: f32 -> bf16 conversions + concatenations + bias builds.
// Linear element space with segment if-chain; 8 elems (16B bf16) per thread.
// ---------------------------------------------------------------------------
__global__ __launch_bounds__(256)
void kPrepW(const float* __restrict__ encw_s, const float* __restrict__ haw,
            const float* __restrict__ fbw, const float* __restrict__ whh,
            const float* __restrict__ wih, const float* __restrict__ fcw,
            const float* __restrict__ hab, const float* __restrict__ fbb,
            const float* __restrict__ bih, const float* __restrict__ bhh,
            short* __restrict__ encw_d, short* __restrict__ wcat_d,
            short* __restrict__ wihe_d, short* __restrict__ wihm_d,
            short* __restrict__ fc_d, float* __restrict__ biascat,
            float* __restrict__ biasg)
{
    long idx = (long)blockIdx.x * 256 + threadIdx.x;
    long e = idx * 8;
    const float* sp = nullptr; short* dp = nullptr; long de = 0;
    if (e < 1048576)       { sp = &encw_s[e]; dp = encw_d; de = e; }
    else if (e < 3407872)  { long u = e - 1048576; long row = u >> 9, col = u & 511;
                             sp = (row < 512) ? &haw[row * 512 + col]
                                : (row < 2560) ? &fbw[(row - 512) * 512 + col]
                                               : &whh[(row - 2560) * 512 + col];
                             dp = wcat_d; de = u; }
    else if (e < 7602176)  { long u = e - 3407872; long row = u >> 11, col = u & 2047;
                             sp = &wih[row * 2560 + 512 + col]; dp = wihe_d; de = u; }
    else if (e < 8650752)  { long u = e - 7602176; long row = u >> 9, col = u & 511;
                             sp = &wih[row * 2560 + col]; dp = wihm_d; de = u; }
    else if (e < 13770752) { long u = e - 8650752; sp = &fcw[u]; dp = fc_d; de = u; }
    else if (e < 13775360) { long u = e - 13770752;
                             for (int j = 0; j < 8; ++j) { long w = u + j;
                                 biascat[w] = (w < 512) ? hab[w] : ((w < 2560) ? fbb[w - 512] : 0.f); }
                             return; }
    else if (e < 13777408) { long u = e - 13775360;
                             for (int j = 0; j < 8; ++j) biasg[u + j] = bih[u + j] + bhh[u + j];
                             return; }
    else return;
    union { short s[8]; int4v v; } u8;
    #pragma unroll
    for (int j = 0; j < 8; ++j) u8.s[j] = f2bf(sp[j]);
    *reinterpret_cast<int4v*>(&dp[de]) = u8.v;
}

// enc f32 -> bf16 (8 elems/thread)
__global__ __launch_bounds__(256)
void kPrepEnc(const float* __restrict__ src, short* __restrict__ dst)
{
    long i = ((long)blockIdx.x * 256 + threadIdx.x) * 8;
    float4 a = *reinterpret_cast<const float4*>(&src[i]);
    float4 b = *reinterpret_cast<const float4*>(&src[i + 4]);
    union { short s[8]; int4v v; } u8;
    u8.s[0]=f2bf(a.x); u8.s[1]=f2bf(a.y); u8.s[2]=f2bf(a.z); u8.s[3]=f2bf(a.w);
    u8.s[4]=f2bf(b.x); u8.s[5]=f2bf(b.y); u8.s[6]=f2bf(b.z); u8.s[7]=f2bf(b.w);
    *reinterpret_cast<int4v*>(&dst[i]) = u8.v;
}

// embedding gather -> embA[r = t*64+b][512] bf16
__global__ __launch_bounds__(256)
void kEmbGather(const float* __restrict__ embw, const int* __restrict__ captions,
                short* __restrict__ embA)
{
    long e = ((long)blockIdx.x * 256 + threadIdx.x) * 8;   // over 1216*512
    int r = (int)(e >> 9), j = (int)(e & 511);
    int t = r >> 6, b = r & 63;
    int tok = captions[b * TT + t];
    const float* sp = &embw[(size_t)tok * EE + j];
    union { short s[8]; int4v v; } u8;
    #pragma unroll
    for (int q = 0; q < 8; ++q) u8.s[q] = f2bf(sp[q]);
    *reinterpret_cast<int4v*>(&embA[e]) = u8.v;
}

// ---------------------------------------------------------------------------
// MFMA bf16 GEMM: C[M,N] = A[M,K] @ W[N,K]^T. Tile 64x64, BK=64, 4 waves,
// wave w owns rows 16w..16w+15 x all 64 cols (4 n-subtiles = 4 MFMA accs).
// LDS XOR-swizzled (st-style) to kill ds_read_b128 bank conflicts.
// AOP: 0 = A bf16; 1 = A f32 (convert during staging)
// WOP: 0 = plain row n0+r (bounds vs Ntot); 1 = gate-interleaved LSTM rows
// EOP: 0 = f32 +bias; 1 = bf16 +bias; 2 = pred (mask/remap); 4 = k-partials
// SWZ: 0 = (x,y,z)=(nb,mb,kz); 1 = att1 XCD-group swizzle; 2 = pred swizzle
// ---------------------------------------------------------------------------
template<int AOP, int WOP, int EOP, int SWZ>
__global__ __launch_bounds__(256)
void kGemm(const void* __restrict__ Ap, int lda, const short* __restrict__ W, int ldw,
           const float* __restrict__ bias, int Ntot,
           float* __restrict__ outF, int ldc, short* __restrict__ outB,
           int nk, const int* __restrict__ lengths)
{
    __shared__ short As[64 * 64];
    __shared__ short Ws[64 * 64];
    int nb, mb, kz;
    if (SWZ == 0) { nb = blockIdx.x; mb = blockIdx.y; kz = blockIdx.z; }
    else if (SWZ == 1) {  // 1568 blocks: group 8 same-A n-blocks per XCD
        int j = blockIdx.x;
        if (j < 1536) { mb = (j >> 6) * 8 + (j & 7); nb = (j >> 3) & 7; }
        else          { int u = j - 1536; mb = 192 + (u >> 3); nb = u & 7; }
        kz = 0;
    } else {              // 3040 blocks: group same-W n-blocks per XCD
        int j = blockIdx.x; int c = j & 7, s = j >> 3;
        mb = s % 19; int u = s / 19; nb = 8 * u + c; kz = 0;
        if (nb * 64 >= Ntot) return;
    }
    const int tid = threadIdx.x;
    const int m0 = mb * 64, n0 = nb * 64, k0 = kz * nk * 64;
    const int w = tid >> 6, l = tid & 63;
    floatx4 acc[4] = {};

    for (int ks = 0; ks < nk; ++ks) {
        int kt = k0 + ks * 64;
        // ---- stage A (64 rows x 64 cols bf16) ----
        if (AOP == 0) {
            const short* A = (const short*)Ap;
            #pragma unroll
            for (int i = 0; i < 2; ++i) {
                int s = tid + i * 256, row = s >> 3, cg = s & 7;
                int4v v = *reinterpret_cast<const int4v*>(&A[(size_t)(m0 + row) * lda + kt + cg * 8]);
                *reinterpret_cast<int4v*>(&As[row * 64 + ((cg ^ (row & 7)) << 3)]) = v;
            }
        } else {
            const float* A = (const float*)Ap;
            #pragma unroll
            for (int i = 0; i < 2; ++i) {
                int s = tid + i * 256, row = s >> 3, cg = s & 7;
                const float* sp = &A[(size_t)(m0 + row) * lda + kt + cg * 8];
                float4 a = *reinterpret_cast<const float4*>(sp);
                float4 b = *reinterpret_cast<const float4*>(sp + 4);
                union { short s[8]; int4v v; } u8;
                u8.s[0]=f2bf(a.x); u8.s[1]=f2bf(a.y); u8.s[2]=f2bf(a.z); u8.s[3]=f2bf(a.w);
                u8.s[4]=f2bf(b.x); u8.s[5]=f2bf(b.y); u8.s[6]=f2bf(b.z); u8.s[7]=f2bf(b.w);
                *reinterpret_cast<int4v*>(&As[row * 64 + ((cg ^ (row & 7)) << 3)]) = u8.v;
            }
        }
        // ---- stage W ----
        #pragma unroll
        for (int i = 0; i < 2; ++i) {
            int s = tid + i * 256, r = s >> 3, cg = s & 7;
            int4v v = {0, 0, 0, 0};
            if (WOP == 1) {
                int wr = 512 * (r >> 4) + (n0 >> 2) + (r & 15);
                v = *reinterpret_cast<const int4v*>(&W[(size_t)wr * ldw + kt + cg * 8]);
            } else {
                int wr = n0 + r;
                if (wr < Ntot)
                    v = *reinterpret_cast<const int4v*>(&W[(size_t)wr * ldw + kt + cg * 8]);
            }
            *reinterpret_cast<int4v*>(&Ws[r * 64 + ((cg ^ (r & 7)) << 3)]) = v;
        }
        __syncthreads();
        // ---- MFMA ----
        #pragma unroll
        for (int kc = 0; kc < 2; ++kc) {
            int arow = 16 * w + (l & 15);
            int cg = 4 * kc + (l >> 4);
            short8 af = *reinterpret_cast<const short8*>(&As[arow * 64 + ((cg ^ (arow & 7)) << 3)]);
            #pragma unroll
            for (int q = 0; q < 4; ++q) {
                int wrow = 16 * q + (l & 15);
                short8 wf = *reinterpret_cast<const short8*>(&Ws[wrow * 64 + ((cg ^ (wrow & 7)) << 3)]);
                acc[q] = __builtin_amdgcn_mfma_f32_16x16x32_bf16(af, wf, acc[q], 0, 0, 0);
            }
        }
        __syncthreads();
    }
    // ---- epilogue: D[row=4*(l>>4)+j (in 16w..), col=l&15 (in 16q..)] ----
    int l4 = l >> 4, l15 = l & 15;
    #pragma unroll
    for (int q = 0; q < 4; ++q) {
        #pragma unroll
        for (int j = 0; j < 4; ++j) {
            int m = m0 + 16 * w + 4 * l4 + j;
            int n = n0 + 16 * q + l15;
            float val = acc[q][j];
            if (EOP == 0) {
                outF[(size_t)m * ldc + n] = val + bias[n];
            } else if (EOP == 1) {
                outB[(size_t)m * ldc + n] = f2bf(val + bias[n]);
            } else if (EOP == 2) {
                if (n < Ntot) {
                    int b = m & 63, tt = m >> 6;
                    bool act = tt < (lengths[b] - 1);
                    outF[((size_t)b * TM1 + tt) * VV + n] = act ? (val + bias[n]) : 0.f;
                }
            } else if (EOP == 4) {  // gate-layout partials: col = 512q + 16nb + l15
                int col = 512 * q + (n0 >> 2) + l15;
                int mloc = m - m0;
                outF[((size_t)kz * 64 + mloc) * 2048 + col] = val;
            }
        }
    }
}

// ---------------------------------------------------------------------------
// f32 init path (precompute only): mean, init GEMM, reduce
// ---------------------------------------------------------------------------
__global__ __launch_bounds__(256)
void kMean(const float* __restrict__ enc, float* __restrict__ mean)
{
    int b = blockIdx.x;
    int k = blockIdx.y * 256 + threadIdx.x;
    const float* eb = &enc[(size_t)b * PP * CENC + k];
    float s0 = 0, s1 = 0, s2 = 0, s3 = 0;
    int p = 0;
    for (; p + 4 <= PP; p += 4) {
        s0 += eb[(size_t)(p + 0) * CENC]; s1 += eb[(size_t)(p + 1) * CENC];
        s2 += eb[(size_t)(p + 2) * CENC]; s3 += eb[(size_t)(p + 3) * CENC];
    }
    for (; p < PP; ++p) s0 += eb[(size_t)p * CENC];
    mean[b * CENC + k] = ((s0 + s1) + (s2 + s3)) * (1.0f / PP);
}

__global__ __launch_bounds__(256)
void gemmInit(const float* __restrict__ Amat, const float* __restrict__ W1,
              const float* __restrict__ W2, float* __restrict__ C)
{
    // C[64][1024] partials: blockIdx.x = n-block (16), blockIdx.z = k-chunk (4, 512 each)
    __shared__ __align__(16) float As_[32][64];
    __shared__ __align__(16) float Ws_[32][64];
    const int tid = threadIdx.x;
    const int n0 = blockIdx.x * 64, kz = blockIdx.z, k0 = kz * 512;
    const int ty = tid >> 4, tx = tid & 15;
    float acc[4][4] = {};
    for (int kt = k0; kt < k0 + 512; kt += 32) {
        #pragma unroll
        for (int i = 0; i < 2; ++i) {
            int idx = tid + i * 256, row = idx >> 3, c4 = (idx & 7) * 4;
            float4 v = *reinterpret_cast<const float4*>(&Amat[(size_t)row * CENC + kt + c4]);
            As_[c4 + 0][row] = v.x; As_[c4 + 1][row] = v.y; As_[c4 + 2][row] = v.z; As_[c4 + 3][row] = v.w;
        }
        #pragma unroll
        for (int i = 0; i < 2; ++i) {
            int idx = tid + i * 256, row = idx >> 3, c4 = (idx & 7) * 4;
            int n = n0 + row;
            const float* wr = (n < 512) ? &W1[(size_t)n * CENC + kt + c4]
                                        : &W2[(size_t)(n - 512) * CENC + kt + c4];
            float4 v = *reinterpret_cast<const float4*>(wr);
            Ws_[c4 + 0][row] = v.x; Ws_[c4 + 1][row] = v.y; Ws_[c4 + 2][row] = v.z; Ws_[c4 + 3][row] = v.w;
        }
        __syncthreads();
        #pragma unroll
        for (int kk = 0; kk < 32; ++kk) {
            float av[4], bv[4];
            *reinterpret_cast<float4*>(av) = *reinterpret_cast<const float4*>(&As_[kk][ty * 4]);
            *reinterpret_cast<float4*>(bv) = *reinterpret_cast<const float4*>(&Ws_[kk][tx * 4]);
            #pragma unroll
            for (int ii = 0; ii < 4; ++ii)
                #pragma unroll
                for (int jj = 0; jj < 4; ++jj)
                    acc[ii][jj] = fmaf(av[ii], bv[jj], acc[ii][jj]);
        }
        __syncthreads();
    }
    #pragma unroll
    for (int ii = 0; ii < 4; ++ii)
        #pragma unroll
        for (int jj = 0; jj < 4; ++jj)
            C[((size_t)kz * 64 + ty * 4 + ii) * 1024 + n0 + tx * 4 + jj] = acc[ii][jj];
}

__global__ __launch_bounds__(256)
void kReduceHC(const float* __restrict__ Pc, const float* __restrict__ hb,
               const float* __restrict__ cb, float* __restrict__ hc,
               short* __restrict__ h16)
{
    int b = blockIdx.x, tid = threadIdx.x;
    for (int j = tid; j < 1024; j += 256) {
        float s = Pc[((size_t)0 * BB + b) * 1024 + j] + Pc[((size_t)1 * BB + b) * 1024 + j]
                + Pc[((size_t)2 * BB + b) * 1024 + j] + Pc[((size_t)3 * BB + b) * 1024 + j];
        s += (j < 512) ? hb[j] : cb[j - 512];
        hc[b * 1024 + j] = s;
        if (j < 512) h16[b * 512 + j] = f2bf(s);
    }
}

// ---------------------------------------------------------------------------
// Step B: e = relu(att1 + att2) @ faw + fab; softmax -> alpha (+ masked out)
// ---------------------------------------------------------------------------
__global__ __launch_bounds__(256)
void kStepB(const short* __restrict__ att1, const float* __restrict__ P3h,
            const float* __restrict__ faw, const float* __restrict__ fab,
            const int* __restrict__ lengths, float* __restrict__ alpha,
            float* __restrict__ alpha_out, int t)
{
    int b = blockIdx.x, tid = threadIdx.x;
    __shared__ float att2s[512];
    __shared__ float fw[512];
    __shared__ float es[PP];
    __shared__ float red[8];
    for (int a = tid; a < 512; a += 256) { att2s[a] = P3h[b * NCAT + a]; fw[a] = faw[a]; }
    __syncthreads();
    int wv = tid >> 6, lane = tid & 63;
    for (int p = wv; p < PP; p += 4) {
        short8 v = *reinterpret_cast<const short8*>(&att1[((size_t)b * PP + p) * 512 + lane * 8]);
        float s = 0.f;
        #pragma unroll
        for (int j = 0; j < 8; ++j) {
            float x = bf2f(v[j]) + att2s[lane * 8 + j];
            s += fmaxf(x, 0.f) * fw[lane * 8 + j];
        }
        #pragma unroll
        for (int off = 32; off > 0; off >>= 1) s += __shfl_down(s, off, 64);
        if (lane == 0) es[p] = s + fab[0];
    }
    __syncthreads();
    float m = -1e30f;
    for (int p = tid; p < PP; p += 256) m = fmaxf(m, es[p]);
    #pragma unroll
    for (int off = 32; off > 0; off >>= 1) m = fmaxf(m, __shfl_down(m, off, 64));
    if (lane == 0) red[wv] = m;
    __syncthreads();
    m = fmaxf(fmaxf(red[0], red[1]), fmaxf(red[2], red[3]));
    float ssum = 0.f;
    for (int p = tid; p < PP; p += 256) { float ev = expf(es[p] - m); es[p] = ev; ssum += ev; }
    #pragma unroll
    for (int off = 32; off > 0; off >>= 1) ssum += __shfl_down(ssum, off, 64);
    if (lane == 0) red[4 + wv] = ssum;
    __syncthreads();
    float inv = 1.f / (red[4] + red[5] + red[6] + red[7]);
    bool active = t < (lengths[b] - 1);
    for (int p = tid; p < PP; p += 256) {
        float al = es[p] * inv;
        alpha[b * PP + p] = al;
        alpha_out[((size_t)b * TM1 + t) * PP + p] = active ? al : 0.f;
    }
}

// ---------------------------------------------------------------------------
// Step C: awe = alpha @ enc[b]; x_enc = sigmoid(graw) * awe -> bf16
// grid (64, 8): 256 cols per block. BF=1: bf16 enc; BF=0: f32 enc.
// ---------------------------------------------------------------------------
template<int BF>
__global__ __launch_bounds__(256)
void kStepC(const void* __restrict__ encp, const float* __restrict__ alpha,
            const float* __restrict__ P3h, short* __restrict__ x16)
{
    int b = blockIdx.x, kc = blockIdx.y, tid = threadIdx.x;
    __shared__ float al[PP];
    __shared__ float part[8][256];
    for (int p = tid; p < PP; p += 256) al[p] = alpha[b * PP + p];
    __syncthreads();
    if (BF == 1) {
        const short* enc16 = (const short*)encp;
        int g = tid & 31, prow = tid >> 5;      // 8 cols/thread, 8 p-lanes
        int k0 = kc * 256 + g * 8;
        float acc[8] = {};
        for (int p = prow; p < PP; p += 8) {
            short8 v = *reinterpret_cast<const short8*>(&enc16[((size_t)b * PP + p) * CENC + k0]);
            float a_ = al[p];
            #pragma unroll
            for (int j = 0; j < 8; ++j) acc[j] = fmaf(bf2f(v[j]), a_, acc[j]);
        }
        *reinterpret_cast<float4*>(&part[prow][g * 8])     = make_float4(acc[0], acc[1], acc[2], acc[3]);
        *reinterpret_cast<float4*>(&part[prow][g * 8 + 4]) = make_float4(acc[4], acc[5], acc[6], acc[7]);
        __syncthreads();
        int c = tid;
        float awe = 0.f;
        #pragma unroll
        for (int pr = 0; pr < 8; ++pr) awe += part[pr][c];
        int k = kc * 256 + c;
        float gate = 1.f / (1.f + expf(-P3h[b * NCAT + 512 + k]));
        x16[(size_t)b * CENC + k] = f2bf(gate * awe);
    } else {
        const float* enc = (const float*)encp;
        int g = tid & 63, prow = tid >> 6;      // 4 cols/thread, 4 p-lanes
        int k0 = kc * 256 + g * 4;
        float acc[4] = {};
        for (int p = prow; p < PP; p += 4) {
            float4 v = *reinterpret_cast<const float4*>(&enc[((size_t)b * PP + p) * CENC + k0]);
            float a_ = al[p];
            acc[0] = fmaf(v.x, a_, acc[0]); acc[1] = fmaf(v.y, a_, acc[1]);
            acc[2] = fmaf(v.z, a_, acc[2]); acc[3] = fmaf(v.w, a_, acc[3]);
        }
        *reinterpret_cast<float4*>(&part[prow][g * 4]) = make_float4(acc[0], acc[1], acc[2], acc[3]);
        __syncthreads();
        int c = tid;
        float awe = part[0][c] + part[1][c] + part[2][c] + part[3][c];
        int k = kc * 256 + c;
        float gate = 1.f / (1.f + expf(-P3h[b * NCAT + 512 + k]));
        x16[(size_t)b * CENC + k] = f2bf(gate * awe);
    }
}

// ---------------------------------------------------------------------------
// Step D2: reduce gate partials + emb part + Whh part; LSTM cell update.
// ---------------------------------------------------------------------------
__global__ __launch_bounds__(256)
void kStepD2(const float* __restrict__ Pg, const float* __restrict__ gates_emb,
             const float* __restrict__ P3h, float* __restrict__ hc,
             short* __restrict__ h16, short* __restrict__ allH, int t)
{
    int b = blockIdx.x, tid = threadIdx.x;
    for (int d = tid; d < 512; d += 256) {
        float g4[4];
        #pragma unroll
        for (int q = 0; q < 4; ++q) {
            int col = q * 512 + d;
            float s = gates_emb[((size_t)t * 64 + b) * 2048 + col] + P3h[b * NCAT + 2560 + col];
            #pragma unroll
            for (int kz = 0; kz < 4; ++kz) s += Pg[((size_t)kz * 64 + b) * 2048 + col];
            g4[q] = s;
        }
        float i_ = 1.f / (1.f + expf(-g4[0]));
        float f_ = 1.f / (1.f + expf(-g4[1]));
        float g_ = tanhf(g4[2]);
        float o_ = 1.f / (1.f + expf(-g4[3]));
        float c_new = f_ * hc[b * 1024 + 512 + d] + i_ * g_;
        float h_new = o_ * tanhf(c_new);
        hc[b * 1024 + 512 + d] = c_new;
        hc[b * 1024 + d] = h_new;
        h16[b * 512 + d] = f2bf(h_new);
        allH[((size_t)t * 64 + b) * 512 + d] = f2bf(h_new);
    }
}

extern "C" void kernel_launch(void* const* d_in, const int* in_sizes, int n_in,
                              void* d_out, int out_size, void* d_ws, size_t ws_size,
                              hipStream_t stream)
{
    const float* enc        = (const float*)d_in[0];
    const int*   captions   = (const int*)d_in[1];
    const int*   lengths    = (const int*)d_in[2];
    const float* enc_att_w  = (const float*)d_in[3];
    const float* enc_att_b  = (const float*)d_in[4];
    const float* hid_att_w  = (const float*)d_in[5];
    const float* hid_att_b  = (const float*)d_in[6];
    const float* full_att_w = (const float*)d_in[7];
    const float* full_att_b = (const float*)d_in[8];
    const float* embw       = (const float*)d_in[9];
    const float* w_ih       = (const float*)d_in[10];
    const float* w_hh       = (const float*)d_in[11];
    const float* b_ih       = (const float*)d_in[12];
    const float* b_hh       = (const float*)d_in[13];
    const float* init_h_w   = (const float*)d_in[14];
    const float* init_h_b   = (const float*)d_in[15];
    const float* init_c_w   = (const float*)d_in[16];
    const float* init_c_b   = (const float*)d_in[17];
    const float* fbeta_w    = (const float*)d_in[18];
    const float* fbeta_b    = (const float*)d_in[19];
    const float* fc_w       = (const float*)d_in[20];
    const float* fc_b       = (const float*)d_in[21];

    float* out_pred  = (float*)d_out;                        // [64][19][10000]
    float* out_alpha = out_pred + (size_t)BB * TM1 * VV;     // [64][19][196]

    // ---- scratch in d_out pred region (all dead before the final pred GEMM)
    char* pr = (char*)d_out;
    short* att1_16   = (short*)pr;                      pr += 12845056;  // 12544x512 bf16
    float* gates_emb = (float*)pr;                      pr += 9961472;   // 1216x2048 f32
    short* embA      = (short*)pr;                      pr += 1245184;   // 1216x512 bf16
    short* wcat16    = (short*)pr;                      pr += 4718592;   // 4608x512 bf16
    short* wihe16    = (short*)pr;                      pr += 8388608;   // 2048x2048 bf16
    short* wihm16    = (short*)pr;                      pr += 2097152;   // 2048x512 bf16
    short* encw16    = (short*)pr;                      pr += 2097152;   // 512x2048 bf16
    float* biascat   = (float*)pr;                      pr += 18432;     // 4608 f32
    float* biasg     = (float*)pr;                      pr += 8192;      // 2048 f32

    // ---- workspace
    char* wp = (char*)d_ws;
    short* fc16  = (short*)wp;  wp += 10240000;   // 10000x512 bf16
    short* allH  = (short*)wp;  wp += 1245184;    // 19x64x512 bf16
    float* P3h   = (float*)wp;  wp += 1179648;    // 64x4608 f32
    float* Pg    = (float*)wp;  wp += 2097152;    // 4x64x2048 f32
    float* hc    = (float*)wp;  wp += 262144;     // 64x1024 f32
    short* h16   = (short*)wp;  wp += 65536;      // 64x512 bf16
    short* x16   = (short*)wp;  wp += 262144;     // 64x2048 bf16
    float* alpha = (float*)wp;  wp += 50176;      // 64x196 f32
    float* mean  = (float*)wp;  wp += 524288;     // 64x2048 f32
    float* hcP   = (float*)wp;  wp += 1048576;    // 4x64x1024 f32
    short* enc16 = (short*)wp;  wp += 51380224;   // 64x196x2048 bf16 (optional)
    const bool full = ((size_t)(wp - (char*)d_ws) <= ws_size);

    // ---- precompute ----
    kPrepW<<<6728, 256, 0, stream>>>(enc_att_w, hid_att_w, fbeta_w, w_hh, w_ih, fc_w,
                                     hid_att_b, fbeta_b, b_ih, b_hh,
                                     encw16, wcat16, wihe16, wihm16, fc16, biascat, biasg);
    if (full) kPrepEnc<<<12544, 256, 0, stream>>>(enc, enc16);
    kEmbGather<<<304, 256, 0, stream>>>(embw, captions, embA);
    kMean<<<dim3(64, 8), 256, 0, stream>>>(enc, mean);
    gemmInit<<<dim3(16, 1, 4), 256, 0, stream>>>(mean, init_h_w, init_c_w, hcP);
    kReduceHC<<<64, 256, 0, stream>>>(hcP, init_h_b, init_c_b, hc, h16);

    // att1 = enc @ enc_att_w^T + b -> bf16 [12544][512]
    if (full)
        kGemm<0, 0, 1, 1><<<1568, 256, 0, stream>>>(enc16, CENC, encw16, CENC,
            enc_att_b, 512, nullptr, 512, att1_16, 32, nullptr);
    else
        kGemm<1, 0, 1, 1><<<1568, 256, 0, stream>>>(enc, CENC, encw16, CENC,
            enc_att_b, 512, nullptr, 512, att1_16, 32, nullptr);

    // gates_emb = embA @ W_ih[:, :512]^T + (b_ih + b_hh)  -> f32 [1216][2048]
    kGemm<0, 0, 0, 0><<<dim3(32, 19, 1), 256, 0, stream>>>(embA, 512, wihm16, 512,
        biasg, 2048, gates_emb, 2048, nullptr, 8, nullptr);

    // ---- sequential decode ----
    for (int t = 0; t < TM1; ++t) {
        // P3h = h @ [hid_att_w ; fbeta_w ; W_hh]^T + biascat  -> [64][4608]
        kGemm<0, 0, 0, 0><<<dim3(72, 1, 1), 256, 0, stream>>>(h16, 512, wcat16, 512,
            biascat, NCAT, P3h, NCAT, nullptr, 8, nullptr);

        kStepB<<<64, 256, 0, stream>>>(att1_16, P3h, full_att_w, full_att_b,
                                       lengths, alpha, out_alpha, t);

        if (full) kStepC<1><<<dim3(64, 8), 256, 0, stream>>>(enc16, alpha, P3h, x16);
        else      kStepC<0><<<dim3(64, 8), 256, 0, stream>>>(enc, alpha, P3h, x16);

        // gate partials: x_enc @ W_ih[:, 512:]^T (gate-interleaved rows), k-split x4
        kGemm<0, 1, 4, 0><<<dim3(32, 1, 4), 256, 0, stream>>>(x16, CENC, wihe16, CENC,
            nullptr, 2048, Pg, 2048, nullptr, 8, nullptr);

        kStepD2<<<64, 256, 0, stream>>>(Pg, gates_emb, P3h, hc, h16, allH, t);
    }

    // ---- pred = allH @ fc_w^T + fc_b (masked, remapped) ----
    kGemm<0, 0, 2, 2><<<3040, 256, 0, stream>>>(allH, 512, fc16, 512,
        fc_b, VV, out_pred, VV, nullptr, 8, lengths);
}